// Round 1
// 110.710 us; speedup vs baseline: 1.0353x; 1.0353x over previous
//
#include <hip/hip_runtime.h>
#include <hip/hip_bf16.h>
#include <math.h>

// Problem constants
#define B_ 4
#define N_ 2048
#define D_ 512
#define H_ 8
#define DH_ 128
#define INNER_ 1024   // H_*DH_
#define W_ 32         // gaussian half-width; exp(-33^2/(2*2.5^2)) ~ 1e-38
#define M_ (B_ * N_)  // 8192

typedef __attribute__((ext_vector_type(8))) short short8;
typedef __attribute__((ext_vector_type(4))) float floatx4;

typedef const __attribute__((address_space(1))) char* gcp;
typedef __attribute__((address_space(3))) char* lcp;

__device__ __forceinline__ unsigned f_to_bf16bits(float f) {
    union { float f; unsigned u; } c; c.f = f;
    return (c.u + 0x7fffu + ((c.u >> 16) & 1u)) >> 16;   // RNE
}
__device__ __forceinline__ float bf16s_to_f(unsigned short s) {
    union { unsigned u; float f; } c; c.u = ((unsigned)s) << 16; return c.f;
}

// ---------------------------------------------------------------------------
// FUSED GEMM1 + banded gaussian blur (blur as MFMA).
// XCD-grouped mapping: XCD k owns row-tiles [k*16, k*16+16) for ALL heads.
//  - x_bf slice per XCD ~1 MB -> L2-resident across the 8 heads of each tile
//  - attn rows [k*1024, (k+1)*1024) (2 MB) written on XCD k's L2, which
//    gemm2 below reads from the SAME XCD -> cross-kernel L2 reuse.
// ---------------------------------------------------------------------------
#define VST 136   // vsT row stride in shorts

__global__ __launch_bounds__(256, 4) void g1_blur(
    const __hip_bfloat16* __restrict__ x_bf,   // [8192, 512]
    const __hip_bfloat16* __restrict__ Wg_t,   // [1024, 512]
    const float* __restrict__ sigma,           // [8]
    __hip_bfloat16* __restrict__ attn)         // [8192, 1024]
{
    __shared__ char smem[35328];
    __hip_bfloat16* Asm = (__hip_bfloat16*)smem;
    __hip_bfloat16* Bsm = (__hip_bfloat16*)(smem + 16384);

    const int tid  = threadIdx.x;
    const int lane = tid & 63;
    const int w    = tid >> 6;
    const int wm   = w >> 1;        // 0..1
    const int wn   = w & 1;         // 0..1
    const int quad = lane >> 4;     // 0..3
    const int cl   = lane & 15;

    // block -> (row-tile, head) with XCD row-grouping
    const int L    = blockIdx.x + 128 * blockIdx.y;   // linear id, 0..1023
    const int xcd  = L & 7;
    const int idx  = L >> 3;        // 0..127
    const int bm   = xcd * 16 + (idx & 15);   // row-tile 0..127
    const int h    = idx >> 4;                // head 0..7
    const int n0   = bm * 64;
    const int nb0  = n0 & (N_ - 1); // row offset within batch

    floatx4 acc[4][4];
    #pragma unroll
    for (int i = 0; i < 4; ++i)
        #pragma unroll
        for (int j = 0; j < 4; ++j) acc[i][j] = (floatx4){0.f, 0.f, 0.f, 0.f};

    const char* Ab = (const char*)x_bf;                              // stride 1024 B
    const char* Bb = (const char*)(Wg_t + (size_t)(h * DH_) * D_);   // stride 1024 B

    for (int k0 = 0; k0 < D_; k0 += 64) {
        #pragma unroll
        for (int it = 0; it < 4; ++it) {
            int o = it * 4096 + tid * 16;   // wave-uniform base + lane*16
            int r = o >> 7;                 // 0..127
            int s = (o >> 4) & 7;
            int c = s ^ (r & 7);            // XOR-row chunk swizzle
            int gr = n0 - W_ + r;
            gr = gr < 0 ? 0 : (gr > M_ - 1 ? M_ - 1 : gr);   // clamp (masked later)
            __builtin_amdgcn_global_load_lds(
                (gcp)(Ab + (size_t)gr * 1024 + k0 * 2 + c * 16), (lcp)(smem + o), 16, 0, 0);
            __builtin_amdgcn_global_load_lds(
                (gcp)(Bb + (size_t)r * 1024 + k0 * 2 + c * 16), (lcp)(smem + 16384 + o), 16, 0, 0);
        }
        __syncthreads();

        const short* As = (const short*)Asm;
        const short* Bs = (const short*)Bsm;
        #pragma unroll
        for (int kk = 0; kk < 2; ++kk) {
            short8 af[4], bf[4];
            int ch = kk * 4 + quad;
            #pragma unroll
            for (int t = 0; t < 4; ++t) {
                int ra = wm * 64 + t * 16 + cl;
                int rb = wn * 64 + t * 16 + cl;
                af[t] = *(const short8*)(As + ra * 64 + ((ch ^ (ra & 7)) * 8));
                bf[t] = *(const short8*)(Bs + rb * 64 + ((ch ^ (rb & 7)) * 8));
            }
            #pragma unroll
            for (int i = 0; i < 4; ++i)
                #pragma unroll
                for (int j = 0; j < 4; ++j)
                    acc[i][j] = __builtin_amdgcn_mfma_f32_16x16x32_bf16(
                        af[i], bf[j], acc[i][j], 0, 0, 0);
        }
        __syncthreads();
    }

    // ---- dump v-tile TRANSPOSED vsT[ch][row] bf16, batch-masked ----
    unsigned short* vsT   = (unsigned short*)smem;
    unsigned short* wtabS = (unsigned short*)(smem + 34816);   // 65 bf16
    float*          winv  = (float*)(smem + 35072);            // 64 f32

    #pragma unroll
    for (int i = 0; i < 4; ++i) {
        #pragma unroll
        for (int j = 0; j < 4; ++j) {
            int ch   = wn * 64 + j * 16 + cl;
            int row0 = wm * 64 + i * 16 + quad * 4;
            unsigned p01 = 0u, p23 = 0u;
            #pragma unroll
            for (int rr = 0; rr < 4; ++rr) {
                int vb = nb0 - W_ + row0 + rr;
                unsigned bits = (vb >= 0 && vb < N_) ? f_to_bf16bits(acc[i][j][rr]) : 0u;
                if (rr < 2) p01 |= bits << (rr * 16);
                else        p23 |= bits << ((rr - 2) * 16);
            }
            unsigned* dst = (unsigned*)(vsT + ch * VST + row0);
            dst[0] = p01; dst[1] = p23;
        }
    }
    if (tid <= 2 * W_) {
        float sig = sigma[h];
        float d = (float)(tid - W_);
        wtabS[tid] = (unsigned short)f_to_bf16bits(__expf(-d * d / (2.0f * sig * sig)));
    }
    __syncthreads();

    if (tid < 64) {
        float ws = 0.f;
        #pragma unroll
        for (int l = 0; l <= 2 * W_; ++l) {
            int vb = nb0 + tid + l - W_;
            ws += (vb >= 0 && vb < N_) ? bf16s_to_f(wtabS[l]) : 0.f;
        }
        winv[tid] = 1.0f / ws;
    }

    // Band A-frags from bf16 wtab (registers only)
    short afr[2][4][8];
    #pragma unroll
    for (int mi = 0; mi < 2; ++mi) {
        int row = wm * 32 + mi * 16 + cl;
        #pragma unroll
        for (int k4 = 0; k4 < 4; ++k4) {
            int lb = k4 * 32 + quad * 8 - row;
            #pragma unroll
            for (int j = 0; j < 8; ++j) {
                int l = lb + j;
                afr[mi][k4][j] = (l >= 0 && l <= 2 * W_) ? (short)wtabS[l] : (short)0;
            }
        }
    }
    __syncthreads();

    floatx4 oacc[2][4];
    #pragma unroll
    for (int mi = 0; mi < 2; ++mi)
        #pragma unroll
        for (int ni = 0; ni < 4; ++ni) oacc[mi][ni] = (floatx4){0.f, 0.f, 0.f, 0.f};

    #pragma unroll
    for (int k4 = 0; k4 < 4; ++k4) {
        short8 bfr[4];
        #pragma unroll
        for (int ni = 0; ni < 4; ++ni) {
            int ch = wn * 64 + ni * 16 + cl;
            bfr[ni] = *(const short8*)((const short*)vsT + ch * VST + k4 * 32 + quad * 8);
        }
        #pragma unroll
        for (int mi = 0; mi < 2; ++mi)
            #pragma unroll
            for (int ni = 0; ni < 4; ++ni)
                oacc[mi][ni] = __builtin_amdgcn_mfma_f32_16x16x32_bf16(
                    *(short8*)afr[mi][k4], bfr[ni], oacc[mi][ni], 0, 0, 0);
    }

    float wv[2][4];
    #pragma unroll
    for (int mi = 0; mi < 2; ++mi)
        #pragma unroll
        for (int r = 0; r < 4; ++r)
            wv[mi][r] = winv[wm * 32 + mi * 16 + quad * 4 + r];

    #pragma unroll
    for (int mi = 0; mi < 2; ++mi) {
        #pragma unroll
        for (int ni = 0; ni < 4; ++ni) {
            int ch = wn * 64 + ni * 16 + cl;
            #pragma unroll
            for (int r = 0; r < 4; ++r) {
                int orow = wm * 32 + mi * 16 + quad * 4 + r;
                attn[(size_t)(n0 + orow) * INNER_ + h * DH_ + ch] =
                    __float2bfloat16(oacc[mi][ni][r] * wv[mi][r]);
            }
        }
    }
}

// ---------------------------------------------------------------------------
// GEMM2: 64x128 tile, BK=64, double-buffered, XCD swizzle aligned with
// g1_blur's writer XCDs (xcd k reads attn rows [k*1024, (k+1)*1024)).
// Per wave: 32x64 output, per k-step 12 ds_read_b128 : 16 MFMA.
// ---------------------------------------------------------------------------
__global__ __launch_bounds__(256, 3) void gemm2_dbuf(
    const __hip_bfloat16* __restrict__ A,     // attn [8192, 1024]
    const __hip_bfloat16* __restrict__ Bt,    // Wout_t [512, 1024]
    float* __restrict__ C)                    // out [8192, 512]
{
    __shared__ char smem[49152];   // 2 x (A 8KB + B 16KB); Cs 32KB aliases after

    const int bid  = blockIdx.x;          // 0..511
    const int xcd  = bid & 7;
    const int idx  = bid >> 3;            // 0..63
    const int bm   = xcd * 16 + (idx & 15);   // 64-row tile, 0..127
    const int bn   = idx >> 4;                // 128-col tile, 0..3

    const int tid  = threadIdx.x;
    const int lane = tid & 63;
    const int w    = tid >> 6;
    const int wm   = w >> 1;        // 0..1  (32-row group)
    const int wn   = w & 1;         // 0..1  (64-col group)
    const int kh   = lane >> 4;     // 0..3
    const int ml   = lane & 15;

    floatx4 acc[2][4];
    #pragma unroll
    for (int i = 0; i < 2; ++i)
        #pragma unroll
        for (int j = 0; j < 4; ++j) acc[i][j] = (floatx4){0.f, 0.f, 0.f, 0.f};

    const char* Ab = (const char*)(A + (size_t)(bm * 64) * INNER_);
    const char* Bb = (const char*)(Bt + (size_t)(bn * 128) * INNER_);

    auto issue = [&](int buf, int k0) {
        #pragma unroll
        for (int it = 0; it < 2; ++it) {    // A: 64 rows x 128 B = 8 KB
            int o = it * 4096 + tid * 16;
            int r = o >> 7;                 // 0..63
            int c = ((o >> 4) & 7) ^ (r & 7);
            __builtin_amdgcn_global_load_lds(
                (gcp)(Ab + (size_t)r * 2048 + k0 * 2 + c * 16),
                (lcp)(smem + buf * 24576 + o), 16, 0, 0);
        }
        #pragma unroll
        for (int it = 0; it < 4; ++it) {    // B: 128 rows x 128 B = 16 KB
            int o = it * 4096 + tid * 16;
            int r = o >> 7;                 // 0..127
            int c = ((o >> 4) & 7) ^ (r & 7);
            __builtin_amdgcn_global_load_lds(
                (gcp)(Bb + (size_t)r * 2048 + k0 * 2 + c * 16),
                (lcp)(smem + buf * 24576 + 8192 + o), 16, 0, 0);
        }
    };
    auto consume = [&](int buf) {
        const short* As = (const short*)(smem + buf * 24576);
        const short* Bs = (const short*)(smem + buf * 24576 + 8192);
        short8 af[2][2], bf[4][2];
        #pragma unroll
        for (int t = 0; t < 2; ++t) {
            int ra = wm * 32 + t * 16 + ml;
            #pragma unroll
            for (int kk = 0; kk < 2; ++kk) {
                int ch = kk * 4 + kh;
                af[t][kk] = *(const short8*)(As + ra * 64 + ((ch ^ (ra & 7)) * 8));
            }
        }
        #pragma unroll
        for (int ni = 0; ni < 4; ++ni) {
            int rb = wn * 64 + ni * 16 + ml;
            #pragma unroll
            for (int kk = 0; kk < 2; ++kk) {
                int ch = kk * 4 + kh;
                bf[ni][kk] = *(const short8*)(Bs + rb * 64 + ((ch ^ (rb & 7)) * 8));
            }
        }
        #pragma unroll
        for (int kk = 0; kk < 2; ++kk)
            #pragma unroll
            for (int i = 0; i < 2; ++i)
                #pragma unroll
                for (int j = 0; j < 4; ++j)
                    acc[i][j] = __builtin_amdgcn_mfma_f32_16x16x32_bf16(
                        af[i][kk], bf[j][kk], acc[i][j], 0, 0, 0);
    };

    const int nk = INNER_ >> 6;   // 16
    issue(0, 0);
    for (int kt = 0; kt < nk; kt += 2) {
        __syncthreads();
        if (kt + 1 < nk) issue(1, (kt + 1) << 6);
        consume(0);
        __syncthreads();
        if (kt + 2 < nk) issue(0, (kt + 2) << 6);
        consume(1);
    }
    __syncthreads();

    float* Cs = (float*)smem;      // [64][128] f32 = 32 KB
    const int rq = lane >> 4;
    const int cl = lane & 15;
    #pragma unroll
    for (int i = 0; i < 2; ++i)
        #pragma unroll
        for (int j = 0; j < 4; ++j)
            #pragma unroll
            for (int r = 0; r < 4; ++r)
                Cs[(wm * 32 + i * 16 + rq * 4 + r) * 128 + wn * 64 + j * 16 + cl] = acc[i][j][r];
    __syncthreads();

    #pragma unroll
    for (int p = 0; p < 8; ++p) {
        int idx2 = p * 256 + tid;
        int rr = idx2 >> 5;             // 0..63
        int cc = (idx2 & 31) * 4;       // 0..124
        float4 vv = *(const float4*)(Cs + rr * 128 + cc);
        *(float4*)(C + (size_t)(bm * 64 + rr) * D_ + bn * 128 + cc) = vv;
    }
}

// ---------------------------------------------------------------------------
// Fused prologue: x cast + plain weight transposes.
// ---------------------------------------------------------------------------
__device__ __forceinline__ void transpose32(
    const float* __restrict__ src, __hip_bfloat16* __restrict__ dst,
    int R, int Cn, int rt, int ct, int tid)
{
    __shared__ float t[32][33];
    int c0 = ct * 32, r0 = rt * 32;
    int lx = tid & 31, ly = tid >> 5;
    #pragma unroll
    for (int i = 0; i < 32; i += 8)
        t[ly + i][lx] = src[(size_t)(r0 + ly + i) * Cn + c0 + lx];
    __syncthreads();
    #pragma unroll
    for (int i = 0; i < 32; i += 8)
        dst[(size_t)(c0 + ly + i) * R + r0 + lx] = __float2bfloat16(t[lx][ly + i]);
}

__global__ __launch_bounds__(256) void prep(
    const float* __restrict__ x, const float* __restrict__ Wg,
    const float* __restrict__ Wout, __hip_bfloat16* __restrict__ x_bf,
    __hip_bfloat16* __restrict__ Wg_t, __hip_bfloat16* __restrict__ Wout_t)
{
    const int bid = blockIdx.x;
    const int tid = threadIdx.x;
    if (bid < 2048) {
        int i = bid * 256 + tid;
        const float4* s = (const float4*)x + (size_t)i * 2;
        float4 a = s[0], b = s[1];
        __hip_bfloat16 o[8] = {
            __float2bfloat16(a.x), __float2bfloat16(a.y), __float2bfloat16(a.z), __float2bfloat16(a.w),
            __float2bfloat16(b.x), __float2bfloat16(b.y), __float2bfloat16(b.z), __float2bfloat16(b.w)};
        *(short8*)(x_bf + (size_t)i * 8) = *(short8*)o;
    } else if (bid < 2560) {
        int id2 = bid - 2048;   // Wg [512,1024] -> Wg_t [1024,512]
        transpose32(Wg, Wg_t, D_, INNER_, id2 >> 5, id2 & 31, tid);
    } else {
        int id2 = bid - 2560;   // Wout [1024,512] -> Wout_t [512,1024]
        transpose32(Wout, Wout_t, INNER_, D_, id2 >> 4, id2 & 15, tid);
    }
}

// ---------------------------------------------------------------------------
extern "C" void kernel_launch(void* const* d_in, const int* in_sizes, int n_in,
                              void* d_out, int out_size, void* d_ws, size_t ws_size,
                              hipStream_t stream) {
    const float* x     = (const float*)d_in[0];
    const float* Wg    = (const float*)d_in[1];
    const float* Wout  = (const float*)d_in[2];
    const float* sigma = (const float*)d_in[3];
    float* out = (float*)d_out;

    char* ws = (char*)d_ws;
    __hip_bfloat16* x_bf   = (__hip_bfloat16*)ws;                           // 8 MB
    __hip_bfloat16* Wg_t   = (__hip_bfloat16*)(ws + (((size_t)8)  << 20));  // 1 MB
    __hip_bfloat16* Wout_t = (__hip_bfloat16*)(ws + (((size_t)9)  << 20));  // 1 MB
    __hip_bfloat16* attn   = (__hip_bfloat16*)(ws + (((size_t)10) << 20));  // 16 MB

    prep<<<dim3(3072), dim3(256), 0, stream>>>(x, Wg, Wout, x_bf, Wg_t, Wout_t);

    // fused v-GEMM + MFMA-blur: XCD-grouped (row-tile, head) mapping
    g1_blur<<<dim3(M_ / 64, H_), dim3(256), 0, stream>>>(x_bf, Wg_t, sigma, attn);

    // out = attn @ Wout, 64x128 tiles, writer-aligned XCD swizzle
    gemm2_dbuf<<<dim3(512), dim3(256), 0, stream>>>(attn, Wout_t, out);
}